// Round 5
// baseline (170.015 us; speedup 1.0000x reference)
//
#include <hip/hip_runtime.h>
#include <math.h>

constexpr int S_ = 4096;
constexpr int B_ = 64;
constexpr int H_ = 256;

// ws float layout:
// 0     : dW [B*H] = 16384
// 16384 : pc [B]
// 16448 : scores [B*S] = 262144

// k1 v2: 64 blocks x 1024 threads; thread=(h=t&255, kc=t>>8) splits the
// k-reduction 4x (64 iters/thread instead of 256) -> 4x less load latency.
__global__ __launch_bounds__(1024) void k1_prep(const float* __restrict__ d,
                                                const float* __restrict__ W_a,
                                                const float* __restrict__ W_p,
                                                const float* __restrict__ v_p,
                                                float* __restrict__ dW,
                                                float* __restrict__ pc) {
  int b = blockIdx.x;
  int t = threadIdx.x;
  int h = t & 255;
  int kc = t >> 8;
  const float* db = d + b * H_;
  float acc_a = 0.f, acc_p = 0.f;
#pragma unroll 8
  for (int k = kc * 64; k < kc * 64 + 64; ++k) {
    float dv = db[k];
    acc_a = fmaf(dv, W_a[k * H_ + h], acc_a);
    acc_p = fmaf(dv, W_p[k * H_ + h], acc_p);
  }
  __shared__ float part[4][256];
  part[kc][h] = acc_a;
  __syncthreads();
  float dwa = 0.f;
  if (t < 256) dwa = part[0][t] + part[1][t] + part[2][t] + part[3][t];
  __syncthreads();
  part[kc][h] = acc_p;
  __syncthreads();
  __shared__ float red[256];
  if (t < 256) {
    dW[b * H_ + t] = dwa;
    float dwp = part[0][t] + part[1][t] + part[2][t] + part[3][t];
    red[t] = tanhf(dwp) * v_p[t];
  }
  __syncthreads();
  for (int st = 128; st > 0; st >>= 1) {
    if (t < st) red[t] += red[t + st];
    __syncthreads();
  }
  if (t == 0) pc[b] = (float)S_ / (1.f + expf(-red[0]));
}

// scores kernel (unchanged from R3/R4 — this round probes its duration by
// launching it 3x; idempotent so results are identical).
__global__ __launch_bounds__(256) void k2_scores(const float* __restrict__ e,
                                                 const float* __restrict__ dW,
                                                 float* __restrict__ scores) {
  int t = threadIdx.x;
  int wave = t >> 6;
  int lane = t & 63;
  int bl = lane >> 2;
  int sub = lane & 3;
  int b = wave * 16 + bl;
  int s0 = blockIdx.x * 4;

  const float4* dW4 = (const float4*)(dW + b * H_);
  float4 wreg[16];
#pragma unroll
  for (int j = 0; j < 16; ++j) wreg[j] = dW4[sub + 4 * j];

  float sc[4];
#pragma unroll
  for (int r = 0; r < 4; ++r) {
    const float4* erow = (const float4*)(e + ((size_t)(s0 + r) * B_ + b) * H_);
    float acc = 0.f;
#pragma unroll
    for (int half = 0; half < 2; ++half) {
      float4 ev[8];
#pragma unroll
      for (int j = 0; j < 8; ++j) ev[j] = erow[sub + 4 * (half * 8 + j)];
#pragma unroll
      for (int j = 0; j < 8; ++j) {
        const float4 wv = wreg[half * 8 + j];
        acc = fmaf(ev[j].x, wv.x, fmaf(ev[j].y, wv.y,
              fmaf(ev[j].z, wv.z, fmaf(ev[j].w, wv.w, acc))));
      }
    }
    acc += __shfl_xor(acc, 1, 64);
    acc += __shfl_xor(acc, 2, 64);
    sc[r] = acc;
  }

  __shared__ float tile[4][64];
  if (sub == 0) {
#pragma unroll
    for (int r = 0; r < 4; ++r) tile[r][b] = sc[r];
  }
  __syncthreads();
  int b_out = t >> 2, r = t & 3;
  scores[b_out * S_ + s0 + r] = tile[r][b_out];
}

// kF v2: 64 blocks x 1024 threads (unchanged from R4).
__global__ __launch_bounds__(1024) void kF(const float* __restrict__ scores,
                                           const float* __restrict__ pc,
                                           const float* __restrict__ e,
                                           const float* __restrict__ d,
                                           const float* __restrict__ lin_w,
                                           const float* __restrict__ lin_b,
                                           float* __restrict__ out,
                                           float* __restrict__ w_out) {
  int b = blockIdx.x;
  int t = threadIdx.x;
  const float* sc = scores + b * S_;
  float v[4];
  float lm = -INFINITY;
#pragma unroll
  for (int k = 0; k < 4; ++k) {
    v[k] = sc[t + k * 1024];
    lm = fmaxf(lm, v[k]);
  }
  __shared__ float red[1024];
  red[t] = lm;
  __syncthreads();
  for (int st = 512; st > 0; st >>= 1) {
    if (t < st) red[t] = fmaxf(red[t], red[t + st]);
    __syncthreads();
  }
  float mb = red[0];
  __syncthreads();
  float ls = 0.f;
#pragma unroll
  for (int k = 0; k < 4; ++k) ls += expf(v[k] - mb);
  red[t] = ls;
  __syncthreads();
  for (int st = 512; st > 0; st >>= 1) {
    if (t < st) red[t] += red[t + st];
    __syncthreads();
  }
  float inv_l = 1.f / red[0];
  float pcb = pc[b];
#pragma unroll
  for (int k = 0; k < 4; ++k) {
    int s = t + k * 1024;
    float diff = pcb - (float)s;
    float p = (fabsf(diff) <= 2.f) ? expf(-0.5f * diff * diff) : 0.f;
    w_out[(size_t)s * B_ + b] = expf(v[k] - mb) * inv_l * p;
  }
  __shared__ float x[512];
  if (t < 256) {
    int s0 = max(0, (int)ceilf(pcb - 2.f));
    int s1 = min(S_ - 1, (int)floorf(pcb + 2.f));
    float ctx = 0.f;
    for (int s = s0; s <= s1; ++s) {
      float diff = pcb - (float)s;
      float wv = expf(sc[s] - mb) * inv_l * expf(-0.5f * diff * diff);
      ctx = fmaf(wv, e[((size_t)s * B_ + b) * H_ + t], ctx);
    }
    x[t] = ctx;
  } else if (t < 512) {
    x[t] = d[b * H_ + (t - 256)];
  }
  __syncthreads();
  int h = t >> 2, part = t & 3;
  const float4* lw = (const float4*)(lin_w + h * 2 * H_) + part * 32;
  const float4* xv = (const float4*)x + part * 32;
  float acc = 0.f;
#pragma unroll 8
  for (int k = 0; k < 32; ++k) {
    float4 a4 = lw[k];
    float4 b4 = xv[k];
    acc += a4.x * b4.x + a4.y * b4.y + a4.z * b4.z + a4.w * b4.w;
  }
  red[t] = acc;
  __syncthreads();
  if (t < 256) {
    float r = red[4 * t] + red[4 * t + 1] + red[4 * t + 2] + red[4 * t + 3] + lin_b[t];
    out[b * H_ + t] = fmaxf(r, 0.f);
  }
}

extern "C" void kernel_launch(void* const* d_in, const int* in_sizes, int n_in,
                              void* d_out, int out_size, void* d_ws, size_t ws_size,
                              hipStream_t stream) {
  const float* e     = (const float*)d_in[0];
  const float* d     = (const float*)d_in[1];
  const float* W_a   = (const float*)d_in[2];
  const float* W_p   = (const float*)d_in[3];
  const float* v_p   = (const float*)d_in[4];
  const float* lin_w = (const float*)d_in[5];
  const float* lin_b = (const float*)d_in[6];

  float* out   = (float*)d_out;        // [1,B,H] = 16384 floats
  float* w_out = out + B_ * H_;        // [S,B]   = 262144 floats

  float* ws     = (float*)d_ws;
  float* dW     = ws;
  float* pc     = ws + 16384;
  float* scores = ws + 16448;

  k1_prep<<<B_, 1024, 0, stream>>>(d, W_a, W_p, v_p, dW, pc);
  // ATTRIBUTION PROBE: k2 launched 3x (idempotent). dur - dur_R4 = 2 * t_k2.
  k2_scores<<<S_ / 4, 256, 0, stream>>>(e, dW, scores);
  k2_scores<<<S_ / 4, 256, 0, stream>>>(e, dW, scores);
  k2_scores<<<S_ / 4, 256, 0, stream>>>(e, dW, scores);
  kF<<<B_, 1024, 0, stream>>>(scores, pc, e, d, lin_w, lin_b, out, w_out);
}

// Round 7
// 74.907 us; speedup vs baseline: 2.2697x; 2.2697x over previous
//
#include <hip/hip_runtime.h>
#include <math.h>

constexpr int S_ = 4096;
constexpr int B_ = 64;
constexpr int H_ = 256;

// ws float layout:
// 0     : dW     [B][H] = 16384
// 16384 : hppart [B][4] = 256    (partial sums of tanh(d@W_p)*v_p per h-chunk)
// 16640 : pcv [B]; 16704 : Mv [B]; 16768 : Lv [B]
// 16832 : scores [B][S] = 262144
// total 278976 floats (~1.12 MB)

// kA: 256 blocks (b x h-chunk of 64), 256 threads (64 h x 4-way k-split).
__global__ __launch_bounds__(256) void kA_prep(const float* __restrict__ d,
                                               const float* __restrict__ W_a,
                                               const float* __restrict__ W_p,
                                               const float* __restrict__ v_p,
                                               float* __restrict__ dW,
                                               float* __restrict__ hppart) {
  const int b = blockIdx.x >> 2;
  const int hc = blockIdx.x & 3;
  const int t = threadIdx.x;
  const int hl = t & 63;
  const int h = hc * 64 + hl;
  const int kc = t >> 6;
  const float* db = d + b * H_;
  float aa = 0.f, ap = 0.f;
#pragma unroll 8
  for (int k = kc * 64; k < kc * 64 + 64; ++k) {
    float dv = db[k];
    aa = fmaf(dv, W_a[k * H_ + h], aa);
    ap = fmaf(dv, W_p[k * H_ + h], ap);
  }
  __shared__ float redA[256];
  __shared__ float redB[256];
  redA[t] = aa;
  redB[t] = ap;
  __syncthreads();
  if (t < 64) {
    float sa = redA[t] + redA[t + 64] + redA[t + 128] + redA[t + 192];
    float sp = redB[t] + redB[t + 64] + redB[t + 128] + redB[t + 192];
    dW[b * H_ + hc * 64 + t] = sa;
    float val = tanhf(sp) * v_p[hc * 64 + t];
#pragma unroll
    for (int off = 32; off > 0; off >>= 1) val += __shfl_xor(val, off, 64);
    if (t == 0) hppart[blockIdx.x] = val;
  }
}

// kB: unchanged proven scores kernel (~45us, ~94% of read floor).
__global__ __launch_bounds__(256) void kB_scores(const float* __restrict__ e,
                                                 const float* __restrict__ dW,
                                                 float* __restrict__ scores) {
  int t = threadIdx.x;
  int wave = t >> 6;
  int lane = t & 63;
  int bl = lane >> 2;
  int sub = lane & 3;
  int b = wave * 16 + bl;
  int s0 = blockIdx.x * 4;

  const float4* dW4 = (const float4*)(dW + b * H_);
  float4 wreg[16];
#pragma unroll
  for (int j = 0; j < 16; ++j) wreg[j] = dW4[sub + 4 * j];

  float sc[4];
#pragma unroll
  for (int r = 0; r < 4; ++r) {
    const float4* erow = (const float4*)(e + ((size_t)(s0 + r) * B_ + b) * H_);
    float acc = 0.f;
#pragma unroll
    for (int half = 0; half < 2; ++half) {
      float4 ev[8];
#pragma unroll
      for (int j = 0; j < 8; ++j) ev[j] = erow[sub + 4 * (half * 8 + j)];
#pragma unroll
      for (int j = 0; j < 8; ++j) {
        const float4 wv = wreg[half * 8 + j];
        acc = fmaf(ev[j].x, wv.x, fmaf(ev[j].y, wv.y,
              fmaf(ev[j].z, wv.z, fmaf(ev[j].w, wv.w, acc))));
      }
    }
    acc += __shfl_xor(acc, 1, 64);
    acc += __shfl_xor(acc, 2, 64);
    sc[r] = acc;
  }

  __shared__ float tile[4][64];
  if (sub == 0) {
#pragma unroll
    for (int r = 0; r < 4; ++r) tile[r][b] = sc[r];
  }
  __syncthreads();
  int b_out = t >> 2, r = t & 3;
  scores[b_out * S_ + s0 + r] = tile[r][b_out];
}

// kC: per-b softmax stats M,L from scores (coalesced reads) + finalize pc.
__global__ __launch_bounds__(256) void kC_stats(const float* __restrict__ scores,
                                                const float* __restrict__ hppart,
                                                float* __restrict__ Mv,
                                                float* __restrict__ Lv,
                                                float* __restrict__ pcv) {
  const int b = blockIdx.x;
  const int t = threadIdx.x;
  const float* sc = scores + b * S_;
  float v[16];
  float lm = -INFINITY;
#pragma unroll
  for (int k = 0; k < 16; ++k) {
    v[k] = sc[t + k * 256];
    lm = fmaxf(lm, v[k]);
  }
  __shared__ float red[256];
  red[t] = lm;
  __syncthreads();
  for (int st = 128; st > 0; st >>= 1) {
    if (t < st) red[t] = fmaxf(red[t], red[t + st]);
    __syncthreads();
  }
  const float M = red[0];
  __syncthreads();
  float ls = 0.f;
#pragma unroll
  for (int k = 0; k < 16; ++k) ls += expf(v[k] - M);
  red[t] = ls;
  __syncthreads();
  for (int st = 128; st > 0; st >>= 1) {
    if (t < st) red[t] += red[t + st];
    __syncthreads();
  }
  if (t == 0) {
    Mv[b] = M;
    Lv[b] = red[0];
    float hp = hppart[4 * b] + hppart[4 * b + 1] + hppart[4 * b + 2] + hppart[4 * b + 3];
    pcv[b] = (float)S_ / (1.f + expf(-hp));
  }
}

// kD: blocks 0..255 -> w_out field, b-major coalesced, score read only in-window.
//     blocks 256..319 -> per-b window context + fused linear + ReLU.
__global__ __launch_bounds__(1024) void kD_out(const float* __restrict__ scores,
                                               const float* __restrict__ Mv,
                                               const float* __restrict__ Lv,
                                               const float* __restrict__ pcv,
                                               const float* __restrict__ e,
                                               const float* __restrict__ d,
                                               const float* __restrict__ lin_w,
                                               const float* __restrict__ lin_b,
                                               float* __restrict__ out,
                                               float* __restrict__ w_out) {
  const int t = threadIdx.x;
  if (blockIdx.x < 256) {
    const int s = blockIdx.x * 16 + (t >> 6);
    const int b = t & 63;
    const float diff = pcv[b] - (float)s;
    float w = 0.f;
    if (fabsf(diff) <= 2.f)
      w = expf(scores[b * S_ + s] - Mv[b]) / Lv[b] * expf(-0.5f * diff * diff);
    w_out[(size_t)s * B_ + b] = w;
    return;
  }
  const int b = blockIdx.x - 256;
  __shared__ float xbuf[512];
  __shared__ float red[1024];
  if (t < 256) {
    const float pcb = pcv[b];
    const float M = Mv[b];
    const float invL = 1.f / Lv[b];
    int s0 = max(0, (int)ceilf(pcb - 2.f));
    int s1 = min(S_ - 1, (int)floorf(pcb + 2.f));
    float ctx = 0.f;
    for (int s = s0; s <= s1; ++s) {
      float diff = pcb - (float)s;
      float wv = expf(scores[b * S_ + s] - M) * invL * expf(-0.5f * diff * diff);
      ctx = fmaf(wv, e[((size_t)s * B_ + b) * H_ + t], ctx);
    }
    xbuf[t] = ctx;
    xbuf[256 + t] = d[b * H_ + t];
  }
  __syncthreads();
  const int h = t >> 2, part = t & 3;
  const float4* lw = (const float4*)(lin_w + h * 2 * H_) + part * 32;
  const float4* xv = (const float4*)xbuf + part * 32;
  float acc = 0.f;
#pragma unroll 8
  for (int k = 0; k < 32; ++k) {
    float4 a4 = lw[k];
    float4 b4 = xv[k];
    acc += a4.x * b4.x + a4.y * b4.y + a4.z * b4.z + a4.w * b4.w;
  }
  red[t] = acc;
  __syncthreads();
  if (t < 256) {
    float r = red[4 * t] + red[4 * t + 1] + red[4 * t + 2] + red[4 * t + 3] + lin_b[t];
    out[b * H_ + t] = fmaxf(r, 0.f);
  }
}

extern "C" void kernel_launch(void* const* d_in, const int* in_sizes, int n_in,
                              void* d_out, int out_size, void* d_ws, size_t ws_size,
                              hipStream_t stream) {
  const float* e     = (const float*)d_in[0];
  const float* dd    = (const float*)d_in[1];
  const float* W_a   = (const float*)d_in[2];
  const float* W_p   = (const float*)d_in[3];
  const float* v_p   = (const float*)d_in[4];
  const float* lin_w = (const float*)d_in[5];
  const float* lin_b = (const float*)d_in[6];

  float* out   = (float*)d_out;        // [1,B,H] = 16384 floats
  float* w_out = out + B_ * H_;        // [S,B]   = 262144 floats

  float* ws     = (float*)d_ws;
  float* dW     = ws;
  float* hppart = ws + 16384;
  float* pcv    = ws + 16640;
  float* Mv     = ws + 16704;
  float* Lv     = ws + 16768;
  float* scores = ws + 16832;

  kA_prep<<<256, 256, 0, stream>>>(dd, W_a, W_p, v_p, dW, hppart);
  kB_scores<<<S_ / 4, 256, 0, stream>>>(e, dW, scores);
  kC_stats<<<B_, 256, 0, stream>>>(scores, hppart, Mv, Lv, pcv);
  kD_out<<<320, 1024, 0, stream>>>(scores, Mv, Lv, pcv, e, dd, lin_w, lin_b, out, w_out);
}